// Round 7
// baseline (421.257 us; speedup 1.0000x reference)
//
#include <hip/hip_runtime.h>
#include <math.h>

#define HALF 64
#define LN_EPS 1e-5f

// gelu_tanh(x) = x * sigmoid(1.5957691*x + 0.0713549*x^3)
#define GC0 -2.3022082f
#define GC1 -0.1029438f

__device__ __forceinline__ float gelu_fast(float x) {
    const float x2 = x * x;
    const float z  = x * fmaf(GC1, x2, GC0);
    const float e  = __builtin_amdgcn_exp2f(z);
    const float sg = __builtin_amdgcn_rcpf(1.0f + e);
    return x * sg;
}

// ---------------------------------------------------------------------------
// init: zero cursor (grid-stride) + block0/wave0 computes analytic-LN consts.
// fp[0..13] = ux,uy,uz,c, Gxx,Gxy,Gxz,Gyy,Gyz,Gzz, px,py,pz,q
// ---------------------------------------------------------------------------
__global__ void __launch_bounds__(256) init_kernel(
    const float* __restrict__ W1, const float* __restrict__ b1,
    int* __restrict__ cursor, float* __restrict__ fp, int N)
{
    const int t = blockIdx.x * 256 + threadIdx.x;
    const int T = gridDim.x * 256;
    for (int i = t; i < N; i += T) cursor[i] = 0;
    if (blockIdx.x == 0 && threadIdx.x < 64) {
        const int k = threadIdx.x;
        const float w0 = W1[k], w1 = W1[HALF + k], w2 = W1[2 * HALF + k], bb = b1[k];
        float v[14] = { w0, w1, w2, bb,
                        w0 * w0, w0 * w1, w0 * w2, w1 * w1, w1 * w2, w2 * w2,
                        w0 * bb, w1 * bb, w2 * bb, bb * bb };
#pragma unroll
        for (int j = 0; j < 14; ++j) {
            float s = v[j];
#pragma unroll
            for (int off = 32; off; off >>= 1) s += __shfl_down(s, off, 64);
            if (k == 0) fp[j] = s * (1.0f / 64.0f);
        }
    }
}

// ---------------------------------------------------------------------------
// histogram of dst
// ---------------------------------------------------------------------------
__global__ void __launch_bounds__(256) hist_kernel(
    const int* __restrict__ dst, int* __restrict__ cursor, int E)
{
    const int e4 = (blockIdx.x * 256 + threadIdx.x) * 4;
    if (e4 + 3 < E) {
        const int4 d = *(const int4*)(dst + e4);
        atomicAdd(&cursor[d.x], 1);
        atomicAdd(&cursor[d.y], 1);
        atomicAdd(&cursor[d.z], 1);
        atomicAdd(&cursor[d.w], 1);
    } else {
        for (int e = e4; e < E; ++e) atomicAdd(&cursor[dst[e]], 1);
    }
}

// ---------------------------------------------------------------------------
// single-block exclusive scan: cursor(counts) -> offsets[N+1]; cursor<-offsets.
// 1024 threads, 4 elems/thread/iter, wave shfl-scans (3 barriers per iter).
// ---------------------------------------------------------------------------
__global__ void __launch_bounds__(1024) scan_kernel(
    int* __restrict__ cursor, int* __restrict__ offsets, int N)
{
    __shared__ int wtot[16];
    __shared__ int wexc[16];
    __shared__ int stot;
    const int t = threadIdx.x;
    const int w = t >> 6, lane = t & 63;
    int carry = 0;
    for (int base = 0; base < N; base += 4096) {
        const int i0 = base + t * 4;
        int c[4];
        if (i0 + 3 < N) {
            *(int4*)c = *(const int4*)(cursor + i0);
        } else {
#pragma unroll
            for (int j = 0; j < 4; ++j) c[j] = (i0 + j < N) ? cursor[i0 + j] : 0;
        }
        const int s = c[0] + c[1] + c[2] + c[3];
        int incl = s;
#pragma unroll
        for (int off = 1; off < 64; off <<= 1) {
            const int v = __shfl_up(incl, off, 64);
            if (lane >= off) incl += v;
        }
        if (lane == 63) wtot[w] = incl;
        __syncthreads();
        if (t < 16) {
            const int v = wtot[t];
            int inc2 = v;
#pragma unroll
            for (int off = 1; off < 16; off <<= 1) {
                const int u = __shfl_up(inc2, off, 64);
                if (t >= off) inc2 += u;
            }
            wexc[t] = inc2 - v;
            if (t == 15) stot = inc2;
        }
        __syncthreads();
        int run = carry + wexc[w] + (incl - s);
#pragma unroll
        for (int j = 0; j < 4; ++j) {
            const int i = i0 + j;
            if (i < N) { offsets[i] = run; cursor[i] = run; }
            run += c[j];
        }
        carry += stot;
        __syncthreads();    // protect wtot/wexc/stot before next iteration
    }
    if (t == 0) offsets[N] = carry;
}

// ---------------------------------------------------------------------------
// fill: 4 edges/thread; geometry once per edge; scatter A[slot] grouped by dst
// ---------------------------------------------------------------------------
__global__ void __launch_bounds__(256) fill_kernel(
    const int* __restrict__ ei, const float* __restrict__ pos,
    const float* __restrict__ fp, int* __restrict__ cursor,
    float4* __restrict__ A, int E)
{
    const int e4 = (blockIdx.x * 256 + threadIdx.x) * 4;
    if (e4 >= E) return;

    int se[4], de[4];
    if (e4 + 3 < E) {
        *(int4*)se = *(const int4*)(ei + e4);
        *(int4*)de = *(const int4*)(ei + E + e4);
    } else {
        for (int j = 0; j < 4; ++j) {
            const int e = e4 + j;
            se[j] = (e < E) ? ei[e] : 0;
            de[j] = (e < E) ? ei[E + e] : 0;
        }
    }
    const float ux = fp[0], uy = fp[1], uz = fp[2], cc = fp[3];
    const float Gxx = fp[4], Gxy = fp[5], Gxz = fp[6];
    const float Gyy = fp[7], Gyz = fp[8], Gzz = fp[9];
    const float px = fp[10], py = fp[11], pz = fp[12], qq = fp[13];

#pragma unroll
    for (int j = 0; j < 4; ++j) {
        const int e = e4 + j;
        if (e >= E) break;
        const int s = se[j], d = de[j];
        const float rx0 = pos[3 * d + 0] - pos[3 * s + 0];
        const float ry0 = pos[3 * d + 1] - pos[3 * s + 1];
        const float rz0 = pos[3 * d + 2] - pos[3 * s + 2];
        const float dist = sqrtf(rx0 * rx0 + ry0 * ry0 + rz0 * rz0);
        const float inv  = 1.0f / (dist + 1e-6f);
        const float rx = rx0 * inv, ry = ry0 * inv, rz = rz0 * inv;

        const float mu  = fmaf(ux, rx, fmaf(uy, ry, fmaf(uz, rz, cc)));
        const float ev2 = Gxx * rx * rx + Gyy * ry * ry + Gzz * rz * rz
                        + 2.0f * (Gxy * rx * ry + Gxz * rx * rz + Gyz * ry * rz
                                  + px * rx + py * ry + pz * rz) + qq;
        const float rstd = rsqrtf(ev2 - mu * mu + LN_EPS);

        const int slot = atomicAdd(&cursor[d], 1);
        A[slot] = make_float4(rx * rstd, ry * rstd, rz * rstd, rstd);
    }
}

// ---------------------------------------------------------------------------
// Node kernel: grid-stride wave per node, lane = channel.
// x = C0*ax + C1*ay + C2*az + C3*aw + Bl  (LN folded); gelu via exp2+rcp.
// 8-wide load batches (8 dwordx4 in flight per wave); epilogue = 4
// independent shfl->fma chains.
// ---------------------------------------------------------------------------
__global__ void __launch_bounds__(256) node_kernel(
    const float4* __restrict__ A,        // [E+8] CSR-ordered (padded)
    const int* __restrict__ offsets,     // [N+1]
    const float* __restrict__ W1, const float* __restrict__ b1,
    const float* __restrict__ ln_g, const float* __restrict__ ln_b,
    const float* __restrict__ W2, const float* __restrict__ b2,
    const float* __restrict__ fp,
    float* __restrict__ out, int N)
{
    __shared__ float sW2[HALF * HALF];
    __shared__ float sb2[HALF];
    const int tid = threadIdx.x;
    for (int i = tid; i < HALF * HALF; i += 256) sW2[i] = W2[i];
    if (tid < HALF) sb2[tid] = b2[tid];
    __syncthreads();

    const int lane = tid & 63;
    const float gl = ln_g[lane];
    const float C0 = gl * (W1[lane]            - fp[0]);
    const float C1 = gl * (W1[HALF + lane]     - fp[1]);
    const float C2 = gl * (W1[2 * HALF + lane] - fp[2]);
    const float C3 = gl * (b1[lane]            - fp[3]);
    const float Bl = ln_b[lane];
    const float b2l = sb2[lane];

    const int wv = blockIdx.x * 4 + (tid >> 6);
    const int nw = gridDim.x * 4;

    for (int n = wv; n < N; n += nw) {
        const int beg = offsets[n];
        const int cnt = offsets[n + 1] - beg;
        const float4* Ap = A + beg;

        float accA = 0.0f, accB = 0.0f;
        int i = 0;
        for (; i + 8 <= cnt; i += 8) {          // full chunks: no guards
            float4 aa[8];
#pragma unroll
            for (int j = 0; j < 8; ++j) aa[j] = Ap[i + j];
#pragma unroll
            for (int j = 0; j < 8; ++j) {
                const float x = fmaf(C0, aa[j].x, fmaf(C1, aa[j].y,
                                  fmaf(C2, aa[j].z, fmaf(C3, aa[j].w, Bl))));
                if (j & 1) accB += gelu_fast(x); else accA += gelu_fast(x);
            }
        }
        if (i < cnt) {                          // one guarded tail chunk (<8)
            const int rem = cnt - i;
            float4 aa[8];
#pragma unroll
            for (int j = 0; j < 8; ++j) aa[j] = Ap[i + j];   // pad-safe
#pragma unroll
            for (int j = 0; j < 8; ++j) {
                const float x = fmaf(C0, aa[j].x, fmaf(C1, aa[j].y,
                                  fmaf(C2, aa[j].z, fmaf(C3, aa[j].w, Bl))));
                const float g = gelu_fast(x);
                const float gm = (j < rem) ? g : 0.0f;
                if (j & 1) accB += gm; else accA += gm;
            }
        }
        const float acc = accA + accB;

        float o0 = 0.0f, o1 = 0.0f, o2 = 0.0f, o3 = 0.0f;
#pragma unroll
        for (int k = 0; k < HALF; k += 4) {     // 4 independent chains
            o0 = fmaf(__shfl(acc, k,     64), sW2[(k    ) * HALF + lane], o0);
            o1 = fmaf(__shfl(acc, k + 1, 64), sW2[(k + 1) * HALF + lane], o1);
            o2 = fmaf(__shfl(acc, k + 2, 64), sW2[(k + 2) * HALF + lane], o2);
            o3 = fmaf(__shfl(acc, k + 3, 64), sW2[(k + 3) * HALF + lane], o3);
        }
        const float o = (o0 + o1) + (o2 + o3);
        const float r = (cnt > 0) ? (o / (float)cnt + b2l) : 0.0f;
        float* orow = out + (size_t)n * (2 * HALF);
        orow[lane] = r;
        orow[HALF + lane] = 0.0f;
    }
}

// ---------------------------------------------------------------------------
extern "C" void kernel_launch(void* const* d_in, const int* in_sizes, int n_in,
                              void* d_out, int out_size, void* d_ws, size_t ws_size,
                              hipStream_t stream) {
    const float* pos = (const float*)d_in[0];
    const int*   ei  = (const int*)d_in[1];
    // d_in[2] = batch (unused)
    const float* W1  = (const float*)d_in[3];
    const float* b1  = (const float*)d_in[4];
    const float* g   = (const float*)d_in[5];
    const float* b   = (const float*)d_in[6];
    const float* W2  = (const float*)d_in[7];
    const float* b2  = (const float*)d_in[8];
    float* out = (float*)d_out;

    const int N = in_sizes[0] / 3;
    const int E = in_sizes[1] / 2;

    // workspace: A[E+8] float4 | cursor[N] | offsets[N+1] | fp[14]
    float4* A      = (float4*)d_ws;
    int* cursor    = (int*)(A + E + 8);
    int* offsets   = cursor + N;
    float* fparams = (float*)(offsets + N + 1);

    init_kernel<<<128, 256, 0, stream>>>(W1, b1, cursor, fparams, N);
    hist_kernel<<<(E / 4 + 255) / 256, 256, 0, stream>>>(ei + E, cursor, E);
    scan_kernel<<<1, 1024, 0, stream>>>(cursor, offsets, N);
    fill_kernel<<<(E / 4 + 255) / 256, 256, 0, stream>>>(ei, pos, fparams, cursor, A, E);
    node_kernel<<<2048, 256, 0, stream>>>(A, offsets, W1, b1, g, b, W2, b2,
                                          fparams, out, N);
}

// Round 8
// 360.576 us; speedup vs baseline: 1.1683x; 1.1683x over previous
//
#include <hip/hip_runtime.h>
#include <math.h>

#define HALF 64
#define LN_EPS 1e-5f

// gelu_tanh(x) = x * sigmoid(1.5957691*x + 0.0713549*x^3)
#define GC0 -2.3022082f
#define GC1 -0.1029438f

__device__ __forceinline__ float gelu_fast(float x) {
    const float x2 = x * x;
    const float z  = x * fmaf(GC1, x2, GC0);
    const float e  = __builtin_amdgcn_exp2f(z);
    const float sg = __builtin_amdgcn_rcpf(1.0f + e);
    return x * sg;
}

// ---------------------------------------------------------------------------
// init: zero cursor (grid-stride) + block0/wave0 computes analytic-LN consts.
// fp[0..13] = ux,uy,uz,c, Gxx,Gxy,Gxz,Gyy,Gyz,Gzz, px,py,pz,q
// ---------------------------------------------------------------------------
__global__ void __launch_bounds__(256) init_kernel(
    const float* __restrict__ W1, const float* __restrict__ b1,
    int* __restrict__ cursor, float* __restrict__ fp, int N)
{
    const int t = blockIdx.x * 256 + threadIdx.x;
    const int T = gridDim.x * 256;
    for (int i = t; i < N; i += T) cursor[i] = 0;
    if (blockIdx.x == 0 && threadIdx.x < 64) {
        const int k = threadIdx.x;
        const float w0 = W1[k], w1 = W1[HALF + k], w2 = W1[2 * HALF + k], bb = b1[k];
        float v[14] = { w0, w1, w2, bb,
                        w0 * w0, w0 * w1, w0 * w2, w1 * w1, w1 * w2, w2 * w2,
                        w0 * bb, w1 * bb, w2 * bb, bb * bb };
#pragma unroll
        for (int j = 0; j < 14; ++j) {
            float s = v[j];
#pragma unroll
            for (int off = 32; off; off >>= 1) s += __shfl_down(s, off, 64);
            if (k == 0) fp[j] = s * (1.0f / 64.0f);
        }
    }
}

// ---------------------------------------------------------------------------
// histogram of dst; atomic return value IS the edge's rank in its bucket —
// persist it so fill needs no atomics at all.
// ---------------------------------------------------------------------------
__global__ void __launch_bounds__(256) hist_kernel(
    const int* __restrict__ dst, int* __restrict__ cursor,
    int* __restrict__ rank, int E)
{
    const int e4 = (blockIdx.x * 256 + threadIdx.x) * 4;
    if (e4 + 3 < E) {
        const int4 d = *(const int4*)(dst + e4);
        int4 r;
        r.x = atomicAdd(&cursor[d.x], 1);
        r.y = atomicAdd(&cursor[d.y], 1);
        r.z = atomicAdd(&cursor[d.z], 1);
        r.w = atomicAdd(&cursor[d.w], 1);
        *(int4*)(rank + e4) = r;
    } else {
        for (int e = e4; e < E; ++e) rank[e] = atomicAdd(&cursor[dst[e]], 1);
    }
}

// ---------------------------------------------------------------------------
// single-block exclusive scan: cursor(counts) -> offsets[N+1].
// 1024 threads, 4 elems/thread/iter, wave shfl-scans.
// ---------------------------------------------------------------------------
__global__ void __launch_bounds__(1024) scan_kernel(
    const int* __restrict__ cursor, int* __restrict__ offsets, int N)
{
    __shared__ int wtot[16];
    __shared__ int wexc[16];
    __shared__ int stot;
    const int t = threadIdx.x;
    const int w = t >> 6, lane = t & 63;
    int carry = 0;
    for (int base = 0; base < N; base += 4096) {
        const int i0 = base + t * 4;
        int c[4];
        if (i0 + 3 < N) {
            *(int4*)c = *(const int4*)(cursor + i0);
        } else {
#pragma unroll
            for (int j = 0; j < 4; ++j) c[j] = (i0 + j < N) ? cursor[i0 + j] : 0;
        }
        const int s = c[0] + c[1] + c[2] + c[3];
        int incl = s;
#pragma unroll
        for (int off = 1; off < 64; off <<= 1) {
            const int v = __shfl_up(incl, off, 64);
            if (lane >= off) incl += v;
        }
        if (lane == 63) wtot[w] = incl;
        __syncthreads();
        if (t < 16) {
            const int v = wtot[t];
            int inc2 = v;
#pragma unroll
            for (int off = 1; off < 16; off <<= 1) {
                const int u = __shfl_up(inc2, off, 64);
                if (t >= off) inc2 += u;
            }
            wexc[t] = inc2 - v;
            if (t == 15) stot = inc2;
        }
        __syncthreads();
        int run = carry + wexc[w] + (incl - s);
#pragma unroll
        for (int j = 0; j < 4; ++j) {
            const int i = i0 + j;
            if (i < N) offsets[i] = run;
            run += c[j];
        }
        carry += stot;
        __syncthreads();    // protect wtot/wexc/stot before next iteration
    }
    if (t == 0) offsets[N] = carry;
}

// ---------------------------------------------------------------------------
// fill (atomic-free): slot = offsets[dst] + rank[e]; geometry once per edge;
// scatter A[slot] grouped by dst.
// ---------------------------------------------------------------------------
__global__ void __launch_bounds__(256) fill_kernel(
    const int* __restrict__ ei, const int* __restrict__ rank,
    const float* __restrict__ pos, const float* __restrict__ fp,
    const int* __restrict__ offsets, float4* __restrict__ A, int E)
{
    const int e4 = (blockIdx.x * 256 + threadIdx.x) * 4;
    if (e4 >= E) return;

    int se[4], de[4], re[4];
    if (e4 + 3 < E) {
        *(int4*)se = *(const int4*)(ei + e4);
        *(int4*)de = *(const int4*)(ei + E + e4);
        *(int4*)re = *(const int4*)(rank + e4);
    } else {
        for (int j = 0; j < 4; ++j) {
            const int e = e4 + j;
            se[j] = (e < E) ? ei[e] : 0;
            de[j] = (e < E) ? ei[E + e] : 0;
            re[j] = (e < E) ? rank[e] : 0;
        }
    }
    const float ux = fp[0], uy = fp[1], uz = fp[2], cc = fp[3];
    const float Gxx = fp[4], Gxy = fp[5], Gxz = fp[6];
    const float Gyy = fp[7], Gyz = fp[8], Gzz = fp[9];
    const float px = fp[10], py = fp[11], pz = fp[12], qq = fp[13];

#pragma unroll
    for (int j = 0; j < 4; ++j) {
        const int e = e4 + j;
        if (e >= E) break;
        const int s = se[j], d = de[j];
        const float rx0 = pos[3 * d + 0] - pos[3 * s + 0];
        const float ry0 = pos[3 * d + 1] - pos[3 * s + 1];
        const float rz0 = pos[3 * d + 2] - pos[3 * s + 2];
        const float dist = sqrtf(rx0 * rx0 + ry0 * ry0 + rz0 * rz0);
        const float inv  = 1.0f / (dist + 1e-6f);
        const float rx = rx0 * inv, ry = ry0 * inv, rz = rz0 * inv;

        const float mu  = fmaf(ux, rx, fmaf(uy, ry, fmaf(uz, rz, cc)));
        const float ev2 = Gxx * rx * rx + Gyy * ry * ry + Gzz * rz * rz
                        + 2.0f * (Gxy * rx * ry + Gxz * rx * rz + Gyz * ry * rz
                                  + px * rx + py * ry + pz * rz) + qq;
        const float rstd = rsqrtf(ev2 - mu * mu + LN_EPS);

        const int slot = offsets[d] + re[j];
        A[slot] = make_float4(rx * rstd, ry * rstd, rz * rstd, rstd);
    }
}

// ---------------------------------------------------------------------------
// Node kernel: persistent grid-stride wave per node, lane = channel.
// GRID MUST BE <= RESIDENT CAPACITY: VGPR=84 -> 6 blocks/CU -> 1536 blocks.
// x = C0*ax + C1*ay + C2*az + C3*aw + Bl  (LN folded); gelu via exp2+rcp.
// 8-wide load batches; epilogue = 4 independent shfl->fma chains.
// ---------------------------------------------------------------------------
__global__ void __launch_bounds__(256) node_kernel(
    const float4* __restrict__ A,        // [E+8] CSR-ordered (padded)
    const int* __restrict__ offsets,     // [N+1]
    const float* __restrict__ W1, const float* __restrict__ b1,
    const float* __restrict__ ln_g, const float* __restrict__ ln_b,
    const float* __restrict__ W2, const float* __restrict__ b2,
    const float* __restrict__ fp,
    float* __restrict__ out, int N)
{
    __shared__ float sW2[HALF * HALF];
    __shared__ float sb2[HALF];
    const int tid = threadIdx.x;
    for (int i = tid; i < HALF * HALF; i += 256) sW2[i] = W2[i];
    if (tid < HALF) sb2[tid] = b2[tid];
    __syncthreads();

    const int lane = tid & 63;
    const float gl = ln_g[lane];
    const float C0 = gl * (W1[lane]            - fp[0]);
    const float C1 = gl * (W1[HALF + lane]     - fp[1]);
    const float C2 = gl * (W1[2 * HALF + lane] - fp[2]);
    const float C3 = gl * (b1[lane]            - fp[3]);
    const float Bl = ln_b[lane];
    const float b2l = sb2[lane];

    const int wv = blockIdx.x * 4 + (tid >> 6);
    const int nw = gridDim.x * 4;

    for (int n = wv; n < N; n += nw) {
        const int beg = offsets[n];
        const int cnt = offsets[n + 1] - beg;
        const float4* Ap = A + beg;

        float accA = 0.0f, accB = 0.0f;
        int i = 0;
        for (; i + 8 <= cnt; i += 8) {          // full chunks: no guards
            float4 aa[8];
#pragma unroll
            for (int j = 0; j < 8; ++j) aa[j] = Ap[i + j];
#pragma unroll
            for (int j = 0; j < 8; ++j) {
                const float x = fmaf(C0, aa[j].x, fmaf(C1, aa[j].y,
                                  fmaf(C2, aa[j].z, fmaf(C3, aa[j].w, Bl))));
                if (j & 1) accB += gelu_fast(x); else accA += gelu_fast(x);
            }
        }
        if (i < cnt) {                          // one guarded tail chunk (<8)
            const int rem = cnt - i;
            float4 aa[8];
#pragma unroll
            for (int j = 0; j < 8; ++j) aa[j] = Ap[i + j];   // pad-safe
#pragma unroll
            for (int j = 0; j < 8; ++j) {
                const float x = fmaf(C0, aa[j].x, fmaf(C1, aa[j].y,
                                  fmaf(C2, aa[j].z, fmaf(C3, aa[j].w, Bl))));
                const float g = gelu_fast(x);
                const float gm = (j < rem) ? g : 0.0f;
                if (j & 1) accB += gm; else accA += gm;
            }
        }
        const float acc = accA + accB;

        float o0 = 0.0f, o1 = 0.0f, o2 = 0.0f, o3 = 0.0f;
#pragma unroll
        for (int k = 0; k < HALF; k += 4) {     // 4 independent chains
            o0 = fmaf(__shfl(acc, k,     64), sW2[(k    ) * HALF + lane], o0);
            o1 = fmaf(__shfl(acc, k + 1, 64), sW2[(k + 1) * HALF + lane], o1);
            o2 = fmaf(__shfl(acc, k + 2, 64), sW2[(k + 2) * HALF + lane], o2);
            o3 = fmaf(__shfl(acc, k + 3, 64), sW2[(k + 3) * HALF + lane], o3);
        }
        const float o = (o0 + o1) + (o2 + o3);
        const float r = (cnt > 0) ? (o / (float)cnt + b2l) : 0.0f;
        float* orow = out + (size_t)n * (2 * HALF);
        orow[lane] = r;
        orow[HALF + lane] = 0.0f;
    }
}

// ---------------------------------------------------------------------------
extern "C" void kernel_launch(void* const* d_in, const int* in_sizes, int n_in,
                              void* d_out, int out_size, void* d_ws, size_t ws_size,
                              hipStream_t stream) {
    const float* pos = (const float*)d_in[0];
    const int*   ei  = (const int*)d_in[1];
    // d_in[2] = batch (unused)
    const float* W1  = (const float*)d_in[3];
    const float* b1  = (const float*)d_in[4];
    const float* g   = (const float*)d_in[5];
    const float* b   = (const float*)d_in[6];
    const float* W2  = (const float*)d_in[7];
    const float* b2  = (const float*)d_in[8];
    float* out = (float*)d_out;

    const int N = in_sizes[0] / 3;
    const int E = in_sizes[1] / 2;

    // workspace: A[E+8] float4 | cursor[N] | offsets[N+1] | rank[E] | fp[14]
    float4* A      = (float4*)d_ws;
    int* cursor    = (int*)(A + E + 8);
    int* offsets   = cursor + N;
    int* rank      = offsets + N + 1;
    float* fparams = (float*)(rank + E);

    init_kernel<<<128, 256, 0, stream>>>(W1, b1, cursor, fparams, N);
    hist_kernel<<<(E / 4 + 255) / 256, 256, 0, stream>>>(ei + E, cursor, rank, E);
    scan_kernel<<<1, 1024, 0, stream>>>(cursor, offsets, N);
    fill_kernel<<<(E / 4 + 255) / 256, 256, 0, stream>>>(ei, rank, pos, fparams,
                                                         offsets, A, E);
    // 1536 = 6 blocks/CU x 256 CUs (VGPR-limited residency for persistent grid)
    node_kernel<<<1536, 256, 0, stream>>>(A, offsets, W1, b1, g, b, W2, b2,
                                          fparams, out, N);
}